// Round 5
// baseline (706.463 us; speedup 1.0000x reference)
//
#include <hip/hip_runtime.h>
#include <hip/hip_cooperative_groups.h>
#include <math.h>

namespace cg = cooperative_groups;

typedef __attribute__((ext_vector_type(8))) __bf16 bf16x8;
typedef __attribute__((ext_vector_type(4))) float floatx4;

#define NROW 16384
#define KCB  8192
#define TAU  0.05f          // gap threshold for exact-recompute guard
#define NNB  32             // KCB / 256 n-blocks

// workspace byte offsets
#define OFF_PACKED 0u                    // 16384*8
#define OFF_A      131072u               // 16384*512*2 = 16777216 (zh|zl dedup)
#define OFF_B      16908288u             // 8192*512*2 = 8388608 (frag-swizzled)
#define OFF_NRM    25296896u             // 8192*4
#define OFF_PM1    25329664u             // 32*16384*4
#define OFF_PM2    27426816u
#define OFF_PIDX   29523968u
#define OFF_PROV   31621120u             // 16384*4
#define OFF_FLAG   31686656u             // 16384*4
#define OFF_HIST   31752192u             // 8192*4
#define OFF_SCAL   31784960u             // 2 floats: loss, plogp

__device__ __forceinline__ unsigned short f2bf(float f) {  // RNE fp32->bf16
  unsigned u = __float_as_uint(f);
  return (unsigned short)((u + 0x7FFFu + ((u >> 16) & 1u)) >> 16);
}
__device__ __forceinline__ float bf2f(unsigned short b) {
  return __uint_as_float(((unsigned)b) << 16);
}
__device__ __forceinline__ unsigned pack2(unsigned short a, unsigned short b) {
  return (unsigned)a | ((unsigned)b << 16);
}
__device__ __forceinline__ void gld16(const void* g, void* l) {
  __builtin_amdgcn_global_load_lds(
      (const __attribute__((address_space(1))) unsigned int*)g,
      (__attribute__((address_space(3))) unsigned int*)l, 16, 0, 0);
}

// ================= fused prep =================
// bid <1024: A-prep (z transpose + hi/lo split, A'[n][512] = [zh|zl])
// 1024..3071: B-prep (frag-swizzled B'[eb][kt32][ct][lane][8], kt32<8=hi else lo)
// 3072..3583: codebook norms (+ hist/scal zero on first 32 blocks)
__global__ __launch_bounds__(256) void prep_k(
    const float* __restrict__ z, const float* __restrict__ cb,
    unsigned short* __restrict__ A, unsigned short* __restrict__ B2,
    float* __restrict__ nrm, int* __restrict__ hist, float* __restrict__ scal) {
  const int tid = threadIdx.x;
  if (blockIdx.x < 1024) {
    __shared__ float t[64][65];
    const int bb = blockIdx.x >> 6;
    const int hw0 = ((blockIdx.x >> 2) & 15) * 64;
    const int c0 = (blockIdx.x & 3) * 64;
    const int cl = tid >> 2, h4 = (tid & 3) * 16;
    const float* src = z + ((size_t)(bb * 256 + c0 + cl)) * 1024 + hw0 + h4;
#pragma unroll
    for (int j = 0; j < 4; ++j) {
      const float4 v = *(const float4*)(src + 4 * j);
      t[cl][h4 + 4 * j + 0] = v.x; t[cl][h4 + 4 * j + 1] = v.y;
      t[cl][h4 + 4 * j + 2] = v.z; t[cl][h4 + 4 * j + 3] = v.w;
    }
    __syncthreads();
    const int hl = tid >> 2, cq = (tid & 3) * 16;
    const size_t n = (size_t)bb * 1024 + hw0 + hl;
    unsigned short hi[16], lo[16];
#pragma unroll
    for (int j = 0; j < 16; ++j) {
      const float f = t[cq + j][hl];
      const unsigned short h = f2bf(f);
      hi[j] = h;
      lo[j] = f2bf(f - bf2f(h));
    }
    unsigned short* dst = A + n * 512 + c0 + cq;
    uint4 h0 = {pack2(hi[0], hi[1]), pack2(hi[2], hi[3]), pack2(hi[4], hi[5]), pack2(hi[6], hi[7])};
    uint4 h1 = {pack2(hi[8], hi[9]), pack2(hi[10], hi[11]), pack2(hi[12], hi[13]), pack2(hi[14], hi[15])};
    uint4 l0 = {pack2(lo[0], lo[1]), pack2(lo[2], lo[3]), pack2(lo[4], lo[5]), pack2(lo[6], lo[7])};
    uint4 l1 = {pack2(lo[8], lo[9]), pack2(lo[10], lo[11]), pack2(lo[12], lo[13]), pack2(lo[14], lo[15])};
    *(uint4*)(dst) = h0;        *(uint4*)(dst + 8) = h1;       // zh at [c]
    *(uint4*)(dst + 256) = l0;  *(uint4*)(dst + 264) = l1;     // zl at [256+c]
  } else if (blockIdx.x < 3072) {
    // one thread per output octet: g = ((eb*16 + kt32)*16 + ct)*64 + l
    const int g = (blockIdx.x - 1024) * 256 + tid;
    const int l = g & 63;
    const int ct = (g >> 6) & 15;
    const int kt32 = (g >> 10) & 15;
    const int eb = g >> 14;
    const int e = eb * 256 + ct * 16 + (l & 15);
    const int quad = l >> 4;
    const int c0 = (kt32 & 7) * 32 + quad * 8;
    const float4 v0 = *(const float4*)(cb + (size_t)e * 256 + c0);
    const float4 v1 = *(const float4*)(cb + (size_t)e * 256 + c0 + 4);
    float f[8] = {v0.x, v0.y, v0.z, v0.w, v1.x, v1.y, v1.z, v1.w};
    unsigned short o[8];
    if (kt32 < 8) {
#pragma unroll
      for (int j = 0; j < 8; ++j) o[j] = f2bf(f[j]);
    } else {
#pragma unroll
      for (int j = 0; j < 8; ++j) {
        const unsigned short h = f2bf(f[j]);
        o[j] = f2bf(f[j] - bf2f(h));
      }
    }
    uint4 w = {pack2(o[0], o[1]), pack2(o[2], o[3]), pack2(o[4], o[5]), pack2(o[6], o[7])};
    *(uint4*)(B2 + (size_t)g * 8) = w;
  } else {
    const int nb512 = blockIdx.x - 3072;     // 0..511
    if (nb512 < 32) hist[nb512 * 256 + tid] = 0;
    if (nb512 == 0 && tid < 2) scal[tid] = 0.f;
    const int row = nb512 * 16 + (tid >> 4);
    const int l16 = tid & 15;
    const float* cr = cb + (size_t)row * 256 + l16 * 16;
    float s = 0.f;
#pragma unroll
    for (int j = 0; j < 4; ++j) {
      const float4 v = *(const float4*)(cr + 4 * j);
      s += v.x * v.x + v.y * v.y + v.z * v.z + v.w * v.w;
    }
    s += __shfl_xor(s, 8); s += __shfl_xor(s, 4);
    s += __shfl_xor(s, 2); s += __shfl_xor(s, 1);
    if (l16 == 0) nrm[row] = s;
  }
}

// ================= main: bf16 MFMA distance GEMM + fused top-2 argmin ========
// 128x256 block, A staged in LDS (16 KB, XOR-swizzled), B frags loaded
// global->VGPR from pre-swizzled B' (no LDS for B: halves LDS bank pressure,
// round-4 model said LDS-bound at 40% MfmaUtil ceiling).
// k-term map: kc 0-3 zh.eh | 4-7 zh.el | 8-11 zl.eh (dedup'd A/B buffers).
__global__ __launch_bounds__(256, 2) void vq_mfma_k(
    const unsigned short* __restrict__ A, const unsigned short* __restrict__ B2,
    const float* __restrict__ nrm, float* __restrict__ pm1,
    float* __restrict__ pm2, int* __restrict__ pidx) {
  __shared__ unsigned short As[128 * 64];  // 16 KB

  const int tid = threadIdx.x;
  const int mb = blockIdx.y, nb = blockIdx.x;
  const int w = tid >> 6, lane = tid & 63;
  const int quad = lane >> 4, lrow = lane & 15;

  const int sr = tid >> 3, ss = tid & 7;
  const int sq = ss ^ (sr & 7);
  const unsigned short* gA = A + (size_t)(mb * 128 + sr) * 512 + sq * 8;
  unsigned short* lA = As + sr * 64 + ss * 8;
  // B' flat: nb*131072 + phys*8192 + ct*512 + lane*8 (elements)
  const unsigned short* bp = B2 + (size_t)nb * 131072 + (size_t)(w * 4) * 512 + lane * 8;

  floatx4 acc[8][4];
#pragma unroll
  for (int i = 0; i < 8; ++i)
#pragma unroll
    for (int j = 0; j < 4; ++j) acc[i][j] = (floatx4){0.f, 0.f, 0.f, 0.f};

  for (int kc = 0; kc < 12; ++kc) {
    const int koA = ((kc & 3) << 6) + (kc >= 8 ? 256 : 0);
#pragma unroll
    for (int i = 0; i < 4; ++i)
      gld16(gA + (size_t)(i * 32) * 512 + koA, lA + i * 32 * 64);
    bf16x8 bfr[2][4];
#pragma unroll
    for (int ks = 0; ks < 2; ++ks) {
      const int phys = (kc * 2 + ks) & 15;    // [eh|el|eh] dedup: 16..23 -> 0..7
#pragma unroll
      for (int nt = 0; nt < 4; ++nt)
        bfr[ks][nt] = *(const bf16x8*)(bp + (size_t)phys * 8192 + nt * 512);
    }
    __syncthreads();
#pragma unroll
    for (int ks = 0; ks < 2; ++ks) {
      bf16x8 af[8];
#pragma unroll
      for (int mt = 0; mt < 8; ++mt) {
        const int row = mt * 16 + lrow;
        const int slot = (ks * 4 + quad) ^ (row & 7);
        af[mt] = *(const bf16x8*)(As + row * 64 + slot * 8);
      }
#pragma unroll
      for (int mt = 0; mt < 8; ++mt)
#pragma unroll
        for (int nt = 0; nt < 4; ++nt)
          acc[mt][nt] = __builtin_amdgcn_mfma_f32_16x16x32_bf16(
              af[mt], bfr[ks][nt], acc[mt][nt], 0, 0, 0);
    }
    __syncthreads();
  }

  // ---- epilogue: score = nrm[k] - 2*dot; top-2 per row over 256 cols ----
  float nr[4];
#pragma unroll
  for (int nt = 0; nt < 4; ++nt) nr[nt] = nrm[nb * 256 + w * 64 + nt * 16 + lrow];

  float* Lm1 = (float*)As;             // overlay (As dead after loop)
  int* Li1 = (int*)(As + 2048);
  float* Lm2 = (float*)(As + 4096);
#pragma unroll
  for (int mt = 0; mt < 8; ++mt) {
#pragma unroll
    for (int p = 0; p < 4; ++p) {
      float m1 = 3e38f, m2 = 3e38f;
      int i1 = 0;
#pragma unroll
      for (int nt = 0; nt < 4; ++nt) {
        const float s = nr[nt] - 2.0f * acc[mt][nt][p];
        const int kg = nb * 256 + w * 64 + nt * 16 + lrow;
        if (s < m1) { m2 = m1; m1 = s; i1 = kg; }
        else m2 = fminf(m2, s);
      }
      for (int d = 1; d < 16; d <<= 1) {   // merge across 16 lrow lanes
        const float om1 = __shfl_xor(m1, d);
        const int oi1 = __shfl_xor(i1, d);
        const float om2 = __shfl_xor(m2, d);
        if (om1 < m1) { m2 = fminf(m1, om2); m1 = om1; i1 = oi1; }
        else          { m2 = fminf(m2, om1); }
      }
      if (lrow == 0) {
        const int rl = mt * 16 + quad * 4 + p;
        Lm1[rl * 4 + w] = m1; Li1[rl * 4 + w] = i1; Lm2[rl * 4 + w] = m2;
      }
    }
  }
  __syncthreads();
  if (tid < 128) {
    float m1 = Lm1[tid * 4], m2 = Lm2[tid * 4];
    int i1 = Li1[tid * 4];
#pragma unroll
    for (int v = 1; v < 4; ++v) {
      const float om1 = Lm1[tid * 4 + v], om2 = Lm2[tid * 4 + v];
      const int oi1 = Li1[tid * 4 + v];
      if (om1 < m1) { m2 = fminf(m1, om2); m1 = om1; i1 = oi1; }
      else          { m2 = fminf(m2, om1); }
    }
    const int r = mb * 128 + tid;
    pm1[(size_t)nb * NROW + r] = m1;
    pm2[(size_t)nb * NROW + r] = m2;
    pidx[(size_t)nb * NROW + r] = i1;
  }
}

// ================= cooperative tail: reduce -> cleanup -> gather -> stats ====
// One launch replaces 5 (round-4 finding: ~25 us fixed overhead per dispatch).
// Grid 256x256, 1 block/CU co-resident.
__global__ __launch_bounds__(256) void tail_k(
    const float* __restrict__ z, const float* __restrict__ cb,
    const float* __restrict__ nrm, const float* __restrict__ pm1,
    const float* __restrict__ pm2, const int* __restrict__ pidx,
    int* __restrict__ prov, int* __restrict__ flag,
    unsigned long long* __restrict__ packed, int* __restrict__ hist,
    float* __restrict__ scal, float* __restrict__ out,
    float* __restrict__ outidxf, float* __restrict__ out_tail) {
  cg::grid_group grid = cg::this_grid();
  const int bid = blockIdx.x, tid = threadIdx.x;
  __shared__ float q[64][257];        // gather staging, bank-clean reads
  __shared__ int kidx[64];
  __shared__ float zr[256];
  __shared__ unsigned long long red[32];
  __shared__ float ls4[4];

  // ---- P0: per-row reduce over 32 nb partials; flag small gaps ----
  if (tid < 64) {
    const int r = bid * 64 + tid;
    float m1 = 3e38f, m2 = 3e38f;
    int i1 = 0;
    for (int nb = 0; nb < NNB; ++nb) {   // ascending k: strict < keeps first
      const float om1 = pm1[(size_t)nb * NROW + r];
      const float om2 = pm2[(size_t)nb * NROW + r];
      const int oi1 = pidx[(size_t)nb * NROW + r];
      if (om1 < m1) { m2 = fminf(m1, om2); m1 = om1; i1 = oi1; }
      else          { m2 = fminf(m2, om1); }
    }
    prov[r] = i1;
    flag[r] = (m2 - m1 < TAU) ? 1 : 0;
    packed[r] = 0xFFFFFFFFFFFFFFFFull;
  }
  grid.sync();

  // ---- P1: exact fp32 recompute for flagged rows (block = rg x k-quarter) ----
  {
    const int rg = bid >> 2, kq = (bid & 3) * 2048;
    const int sub = tid & 7, kof = tid >> 3, c0 = sub * 32;
    for (int rr = 0; rr < 256; ++rr) {
      const int r = rg * 256 + rr;
      if (!flag[r]) continue;           // block-uniform branch
      zr[tid] = z[((size_t)((r >> 10) * 256 + tid)) * 1024 + (r & 1023)];
      __syncthreads();
      unsigned long long best = 0xFFFFFFFFFFFFFFFFull;
      for (int it = 0; it < 64; ++it) {
        const int k = kq + it * 32 + kof;
        const float* cr = cb + (size_t)k * 256 + c0;
        float p = 0.f;
#pragma unroll
        for (int c = 0; c < 32; c += 4) {
          const float4 v = *(const float4*)(cr + c);
          p += v.x * zr[c0 + c] + v.y * zr[c0 + c + 1] +
               v.z * zr[c0 + c + 2] + v.w * zr[c0 + c + 3];
        }
        p += __shfl_down(p, 4); p += __shfl_down(p, 2); p += __shfl_down(p, 1);
        if (sub == 0) {
          const float s = nrm[k] - 2.f * p;
          unsigned u = __float_as_uint(s);
          u ^= (unsigned)((int)u >> 31) | 0x80000000u;   // sortable float
          const unsigned long long pk =
              ((unsigned long long)u << 32) | (unsigned)k;
          best = best < pk ? best : pk;
        }
      }
      if (sub == 0) red[kof] = best;
      __syncthreads();
      if (tid == 0) {
        unsigned long long b = red[0];
#pragma unroll
        for (int i = 1; i < 32; ++i) b = b < red[i] ? b : red[i];
        atomicMin(packed + r, b);
      }
      __syncthreads();
    }
  }
  grid.sync();

  // ---- P2: finalize idx + hist + gather cb rows + out + loss ----
  {
    const int r0 = bid * 64;
    if (tid < 64) {
      const int r = r0 + tid;
      const int idx = flag[r] ? (int)(packed[r] & 0xFFFFFFFFull) : prov[r];
      kidx[tid] = idx;
      outidxf[r] = (float)idx;
      atomicAdd(&hist[idx], 1);
    }
    __syncthreads();
    const int wv = tid >> 6, lane = tid & 63;
    for (int it = 0; it < 16; ++it) {
      const int rr = it * 4 + wv;
      const float4 v = *(const float4*)(cb + (size_t)kidx[rr] * 256 + lane * 4);
      q[rr][lane * 4 + 0] = v.x; q[rr][lane * 4 + 1] = v.y;
      q[rr][lane * 4 + 2] = v.z; q[rr][lane * 4 + 3] = v.w;
    }
    __syncthreads();
    const int b = r0 >> 10, hw0 = r0 & 1023;
    float lsum = 0.f;
    for (int co = 0; co < 256; co += 4) {
      const int c = co + wv;
      const size_t e = (((size_t)(b * 256 + c)) << 10) + hw0 + lane;
      const float zv = z[e];
      const float d = q[lane][c] - zv;
      out[e] = zv + d;                  // mirrors z + (q - z)
      lsum += d * d;
    }
    for (int off = 32; off; off >>= 1) lsum += __shfl_down(lsum, off);
    if (lane == 0) ls4[wv] = lsum;
    __syncthreads();
    if (tid == 0) atomicAdd(&scal[0], ls4[0] + ls4[1] + ls4[2] + ls4[3]);
  }
  grid.sync();

  // ---- P3: perplexity partial (block covers 32 hist bins) ----
  {
    float part = 0.f;
    if (tid < 32) {
      const float p = (float)hist[bid * 32 + tid] * (1.0f / 16384.0f);
      part = p * logf(fmaxf(p, 1e-10f));
    }
    if (tid < 64) {
      part += __shfl_down(part, 16); part += __shfl_down(part, 8);
      part += __shfl_down(part, 4);  part += __shfl_down(part, 2);
      part += __shfl_down(part, 1);
      if (tid == 0) atomicAdd(&scal[1], part);
    }
  }
  grid.sync();

  // ---- P4: scalars ----
  if (bid == 0 && tid == 0) {
    out_tail[0] = expf(-scal[1]);                 // perplexity
    const float mean = scal[0] * (1.0f / 4194304.0f);
    out_tail[1] = mean;                           // loss_vq
    out_tail[2] = mean;                           // loss_commit
  }
}

extern "C" void kernel_launch(void* const* d_in, const int* in_sizes, int n_in,
                              void* d_out, int out_size, void* d_ws,
                              size_t ws_size, hipStream_t stream) {
  const float* z = (const float*)d_in[0];
  const float* cb = (const float*)d_in[1];
  float* out = (float*)d_out;
  char* ws = (char*)d_ws;

  unsigned long long* packed = (unsigned long long*)(ws + OFF_PACKED);
  unsigned short* A = (unsigned short*)(ws + OFF_A);
  unsigned short* B2 = (unsigned short*)(ws + OFF_B);
  float* nrm = (float*)(ws + OFF_NRM);
  float* pm1 = (float*)(ws + OFF_PM1);
  float* pm2 = (float*)(ws + OFF_PM2);
  int* pidx = (int*)(ws + OFF_PIDX);
  int* prov = (int*)(ws + OFF_PROV);
  int* flag = (int*)(ws + OFF_FLAG);
  int* hist = (int*)(ws + OFF_HIST);
  float* scal = (float*)(ws + OFF_SCAL);
  float* outidxf = out + 4194304;
  float* out_tail = out + 4210688;

  prep_k<<<3584, 256, 0, stream>>>(z, cb, A, B2, nrm, hist, scal);
  vq_mfma_k<<<dim3(NNB, 128), 256, 0, stream>>>(A, B2, nrm, pm1, pm2, pidx);

  void* args[] = {(void*)&z,    (void*)&cb,   (void*)&nrm,  (void*)&pm1,
                  (void*)&pm2,  (void*)&pidx, (void*)&prov, (void*)&flag,
                  (void*)&packed, (void*)&hist, (void*)&scal, (void*)&out,
                  (void*)&outidxf, (void*)&out_tail};
  hipLaunchCooperativeKernel((void*)tail_k, dim3(256), dim3(256), args, 0,
                             stream);
}

// Round 6
// 589.109 us; speedup vs baseline: 1.1992x; 1.1992x over previous
//
#include <hip/hip_runtime.h>
#include <math.h>

typedef __attribute__((ext_vector_type(8))) __bf16 bf16x8;
typedef __attribute__((ext_vector_type(4))) float floatx4;

#define NROW 16384
#define KCB  8192
#define TAU  0.05f          // gap threshold for exact-recompute guard
#define NNB  32             // KCB / 256 n-blocks

// workspace byte offsets
#define OFF_PACKED 0u                    // 16384*8
#define OFF_A      131072u               // 16384*512*2 (zh|zl dedup)
#define OFF_B      16908288u             // 8192*512*2 (eh|el dedup)
#define OFF_ZT     25296896u             // 16384*256*4 fp32 z transposed
#define OFF_NRM    42074112u             // 8192*4
#define OFF_PM1    42106880u             // 32*16384*4
#define OFF_PM2    44204032u
#define OFF_PIDX   46301184u
#define OFF_FIDX   48398336u             // 16384*4
#define OFF_LIST   48463872u             // 16384*4
#define OFF_HIST   48529408u             // 8192*4
#define OFF_MISC   48562176u             // [0] loss f32, [1] cnt, [2] done, [3] done2

__device__ __forceinline__ unsigned short f2bf(float f) {  // RNE fp32->bf16
  unsigned u = __float_as_uint(f);
  return (unsigned short)((u + 0x7FFFu + ((u >> 16) & 1u)) >> 16);
}
__device__ __forceinline__ float bf2f(unsigned short b) {
  return __uint_as_float(((unsigned)b) << 16);
}
__device__ __forceinline__ unsigned pack2(unsigned short a, unsigned short b) {
  return (unsigned)a | ((unsigned)b << 16);
}
__device__ __forceinline__ void gld16(const void* g, void* l) {
  __builtin_amdgcn_global_load_lds(
      (const __attribute__((address_space(1))) unsigned int*)g,
      (__attribute__((address_space(3))) unsigned int*)l, 16, 0, 0);
}

// ================= fused prep =================
// bid <1024: A-prep (z transpose -> A'[n][512]=[zh|zl] bf16 + zt[n][256] fp32)
// 1024..3071: B-prep (B'[e][512]=[eh|el] bf16 + norms)
// 3072..3103: zero hist (+ misc on first)
__global__ __launch_bounds__(256) void prep_k(
    const float* __restrict__ z, const float* __restrict__ cb,
    unsigned short* __restrict__ A, unsigned short* __restrict__ B,
    float* __restrict__ zt, float* __restrict__ nrm, int* __restrict__ hist,
    int* __restrict__ misc) {
  const int tid = threadIdx.x;
  if (blockIdx.x < 1024) {
    __shared__ float t[64][65];
    const int bb = blockIdx.x >> 6;
    const int hw0 = ((blockIdx.x >> 2) & 15) * 64;
    const int c0 = (blockIdx.x & 3) * 64;
    const int cl = tid >> 2, h4 = (tid & 3) * 16;
    const float* src = z + ((size_t)(bb * 256 + c0 + cl)) * 1024 + hw0 + h4;
#pragma unroll
    for (int j = 0; j < 4; ++j) {
      const float4 v = *(const float4*)(src + 4 * j);
      t[cl][h4 + 4 * j + 0] = v.x; t[cl][h4 + 4 * j + 1] = v.y;
      t[cl][h4 + 4 * j + 2] = v.z; t[cl][h4 + 4 * j + 3] = v.w;
    }
    __syncthreads();
    const int hl = tid >> 2, cq = (tid & 3) * 16;
    const size_t n = (size_t)bb * 1024 + hw0 + hl;
    float fv[16];
    unsigned short hi[16], lo[16];
#pragma unroll
    for (int j = 0; j < 16; ++j) {
      const float f = t[cq + j][hl];
      fv[j] = f;
      const unsigned short h = f2bf(f);
      hi[j] = h;
      lo[j] = f2bf(f - bf2f(h));
    }
    unsigned short* dst = A + n * 512 + c0 + cq;
    uint4 h0 = {pack2(hi[0], hi[1]), pack2(hi[2], hi[3]), pack2(hi[4], hi[5]), pack2(hi[6], hi[7])};
    uint4 h1 = {pack2(hi[8], hi[9]), pack2(hi[10], hi[11]), pack2(hi[12], hi[13]), pack2(hi[14], hi[15])};
    uint4 l0 = {pack2(lo[0], lo[1]), pack2(lo[2], lo[3]), pack2(lo[4], lo[5]), pack2(lo[6], lo[7])};
    uint4 l1 = {pack2(lo[8], lo[9]), pack2(lo[10], lo[11]), pack2(lo[12], lo[13]), pack2(lo[14], lo[15])};
    *(uint4*)(dst) = h0;        *(uint4*)(dst + 8) = h1;       // zh at [c]
    *(uint4*)(dst + 256) = l0;  *(uint4*)(dst + 264) = l1;     // zl at [256+c]
    float* zp = zt + n * 256 + c0 + cq;
#pragma unroll
    for (int j = 0; j < 4; ++j) {
      float4 v = {fv[4 * j], fv[4 * j + 1], fv[4 * j + 2], fv[4 * j + 3]};
      *(float4*)(zp + 4 * j) = v;
    }
  } else if (blockIdx.x < 3072) {
    const int w = tid >> 6, lane = tid & 63;
    const int row = (blockIdx.x - 1024) * 4 + w;
    const float4 v = *(const float4*)(cb + (size_t)row * 256 + lane * 4);
    float s = v.x * v.x + v.y * v.y + v.z * v.z + v.w * v.w;
    float f[4] = {v.x, v.y, v.z, v.w};
    ushort4 hv, lv;
    unsigned short* hp = (unsigned short*)&hv;
    unsigned short* lp = (unsigned short*)&lv;
#pragma unroll
    for (int j = 0; j < 4; ++j) {
      const unsigned short h = f2bf(f[j]);
      hp[j] = h;
      lp[j] = f2bf(f[j] - bf2f(h));
    }
    unsigned short* dst = B + (size_t)row * 512 + lane * 4;
    *(ushort4*)(dst) = hv;          // eh
    *(ushort4*)(dst + 256) = lv;    // el
    for (int off = 32; off; off >>= 1) s += __shfl_down(s, off);
    if (lane == 0) nrm[row] = s;
  } else {
    const int i = blockIdx.x - 3072;   // 0..31
    hist[i * 256 + tid] = 0;
    if (i == 0 && tid < 4) misc[tid] = 0;
  }
}

// ================= main: bf16 MFMA distance GEMM + fused top-2 argmin ========
// R4-proven structure (272 us, MfmaUtil 33%, conflicts ~0). Only change:
// dedup'd A'[512]/B'[512] with per-kc offset remap (LDS bytes identical).
// terms: kc 0-3 zh.eh | 4-7 zh.el | 8-11 zl.eh
__global__ __launch_bounds__(256, 2) void vq_mfma_k(
    const unsigned short* __restrict__ A, const unsigned short* __restrict__ Bm,
    const float* __restrict__ nrm, float* __restrict__ pm1,
    float* __restrict__ pm2, int* __restrict__ pidx) {
  __shared__ unsigned short As[128 * 64];  // 16 KB
  __shared__ unsigned short Bs[256 * 64];  // 32 KB

  const int tid = threadIdx.x;
  const int mb = blockIdx.y, nb = blockIdx.x;
  const int w = tid >> 6, lane = tid & 63;
  const int quad = lane >> 4, lrow = lane & 15;

  const int sr = tid >> 3, ss = tid & 7;
  const int sq = ss ^ (sr & 7);
  const unsigned short* gA = A + (size_t)(mb * 128 + sr) * 512 + sq * 8;
  const unsigned short* gB = Bm + (size_t)(nb * 256 + sr) * 512 + sq * 8;
  unsigned short* lA = As + sr * 64 + ss * 8;
  unsigned short* lB = Bs + sr * 64 + ss * 8;

  floatx4 acc[8][4];
#pragma unroll
  for (int i = 0; i < 8; ++i)
#pragma unroll
    for (int j = 0; j < 4; ++j) acc[i][j] = (floatx4){0.f, 0.f, 0.f, 0.f};

  for (int kc = 0; kc < 12; ++kc) {
    const int koA = ((kc & 3) << 6) + (kc >= 8 ? 256 : 0);
    const int koB = ((kc & 3) << 6) + ((kc >= 4 && kc < 8) ? 256 : 0);
#pragma unroll
    for (int i = 0; i < 4; ++i)
      gld16(gA + (size_t)(i * 32) * 512 + koA, lA + i * 32 * 64);
#pragma unroll
    for (int i = 0; i < 8; ++i)
      gld16(gB + (size_t)(i * 32) * 512 + koB, lB + i * 32 * 64);
    __syncthreads();
#pragma unroll
    for (int ks = 0; ks < 2; ++ks) {
      bf16x8 af[8], bf[4];
#pragma unroll
      for (int mt = 0; mt < 8; ++mt) {
        const int row = mt * 16 + lrow;
        const int slot = (ks * 4 + quad) ^ (row & 7);
        af[mt] = *(const bf16x8*)(As + row * 64 + slot * 8);
      }
#pragma unroll
      for (int nt = 0; nt < 4; ++nt) {
        const int row = w * 64 + nt * 16 + lrow;
        const int slot = (ks * 4 + quad) ^ (row & 7);
        bf[nt] = *(const bf16x8*)(Bs + row * 64 + slot * 8);
      }
#pragma unroll
      for (int mt = 0; mt < 8; ++mt)
#pragma unroll
        for (int nt = 0; nt < 4; ++nt)
          acc[mt][nt] = __builtin_amdgcn_mfma_f32_16x16x32_bf16(
              af[mt], bf[nt], acc[mt][nt], 0, 0, 0);
    }
    __syncthreads();
  }

  // ---- epilogue: score = nrm[k] - 2*dot; top-2 per row over 256 cols ----
  float nr[4];
#pragma unroll
  for (int nt = 0; nt < 4; ++nt) nr[nt] = nrm[nb * 256 + w * 64 + nt * 16 + lrow];

  float* Lm1 = (float*)As;             // overlay (As dead after loop)
  int* Li1 = (int*)(As + 2048);
  float* Lm2 = (float*)(As + 4096);
#pragma unroll
  for (int mt = 0; mt < 8; ++mt) {
#pragma unroll
    for (int p = 0; p < 4; ++p) {
      float m1 = 3e38f, m2 = 3e38f;
      int i1 = 0;
#pragma unroll
      for (int nt = 0; nt < 4; ++nt) {
        const float s = nr[nt] - 2.0f * acc[mt][nt][p];
        const int kg = nb * 256 + w * 64 + nt * 16 + lrow;
        if (s < m1) { m2 = m1; m1 = s; i1 = kg; }
        else m2 = fminf(m2, s);
      }
      for (int d = 1; d < 16; d <<= 1) {   // merge across 16 lrow lanes
        const float om1 = __shfl_xor(m1, d);
        const int oi1 = __shfl_xor(i1, d);
        const float om2 = __shfl_xor(m2, d);
        if (om1 < m1) { m2 = fminf(m1, om2); m1 = om1; i1 = oi1; }
        else          { m2 = fminf(m2, om1); }
      }
      if (lrow == 0) {
        const int rl = mt * 16 + quad * 4 + p;
        Lm1[rl * 4 + w] = m1; Li1[rl * 4 + w] = i1; Lm2[rl * 4 + w] = m2;
      }
    }
  }
  __syncthreads();
  if (tid < 128) {
    float m1 = Lm1[tid * 4], m2 = Lm2[tid * 4];
    int i1 = Li1[tid * 4];
#pragma unroll
    for (int v = 1; v < 4; ++v) {
      const float om1 = Lm1[tid * 4 + v], om2 = Lm2[tid * 4 + v];
      const int oi1 = Li1[tid * 4 + v];
      if (om1 < m1) { m2 = fminf(m1, om2); m1 = om1; i1 = oi1; }
      else          { m2 = fminf(m2, om1); }
    }
    const int r = mb * 128 + tid;
    pm1[(size_t)nb * NROW + r] = m1;
    pm2[(size_t)nb * NROW + r] = m2;
    pidx[(size_t)nb * NROW + r] = i1;
  }
}

// ================= reduce partials + provisional finalize =================
__global__ __launch_bounds__(256) void reduce_k(
    const float* __restrict__ pm1, const float* __restrict__ pm2,
    const int* __restrict__ pidx, int* __restrict__ fidx,
    float* __restrict__ outidxf, int* __restrict__ hist,
    unsigned long long* __restrict__ packed, int* __restrict__ list,
    int* __restrict__ misc) {
  const int r = blockIdx.x * 256 + threadIdx.x;
  float m1 = 3e38f, m2 = 3e38f;
  int i1 = 0;
  for (int nb = 0; nb < NNB; ++nb) {   // ascending k: strict < keeps first
    const float om1 = pm1[(size_t)nb * NROW + r];
    const float om2 = pm2[(size_t)nb * NROW + r];
    const int oi1 = pidx[(size_t)nb * NROW + r];
    if (om1 < m1) { m2 = fminf(m1, om2); m1 = om1; i1 = oi1; }
    else          { m2 = fminf(m2, om1); }
  }
  fidx[r] = i1;
  outidxf[r] = (float)i1;
  atomicAdd(&hist[i1], 1);
  if (m2 - m1 < TAU) {
    packed[r] = 0xFFFFFFFFFFFFFFFFull;
    const int p = atomicAdd(&misc[1], 1);
    list[p] = r;
  }
}

// ================= exact fp32 recompute (batched) + last-block fixup ========
// 512 blocks x 16 k each: cb rows cached in registers ONCE, all flagged rows
// streamed through LDS (round-5 lesson: per-row cb re-reads were ~730 MB).
__global__ __launch_bounds__(256) void cleanup_k(
    const float* __restrict__ zt, const float* __restrict__ cb,
    const float* __restrict__ nrm, const int* __restrict__ list,
    int* __restrict__ misc, unsigned long long* __restrict__ packed,
    int* __restrict__ fidx, float* __restrict__ outidxf,
    int* __restrict__ hist) {
  __shared__ float zr[16][256];
  __shared__ int lidx[16];
  __shared__ unsigned long long wred[16][4];
  __shared__ int isLast;
  const int tid = threadIdx.x;
  const int lane = tid & 63, wv = tid >> 6;
  const int nf = misc[1];
  const int k = blockIdx.x * 16 + (tid >> 4);
  const int cs1 = tid & 15;
  float creg[16];
#pragma unroll
  for (int j = 0; j < 16; ++j) creg[j] = cb[(size_t)k * 256 + cs1 + 16 * j];
  const float nk = nrm[k];

  for (int c0 = 0; c0 < nf; c0 += 16) {
    if (tid < 16) lidx[tid] = list[(c0 + tid < nf) ? (c0 + tid) : c0];
    __syncthreads();
#pragma unroll
    for (int j = 0; j < 16; ++j)
      zr[j][tid] = zt[(size_t)lidx[j] * 256 + tid];
    __syncthreads();
    const int rmax = (nf - c0 < 16) ? (nf - c0) : 16;
    for (int rr = 0; rr < rmax; ++rr) {
      float p = 0.f;
#pragma unroll
      for (int j = 0; j < 16; ++j) p += creg[j] * zr[rr][cs1 + 16 * j];
      p += __shfl_xor(p, 1); p += __shfl_xor(p, 2);
      p += __shfl_xor(p, 4); p += __shfl_xor(p, 8);
      unsigned long long v = 0xFFFFFFFFFFFFFFFFull;
      if (cs1 == 0) {
        const float s = nk - 2.f * p;
        unsigned u = __float_as_uint(s);
        u ^= (unsigned)((int)u >> 31) | 0x80000000u;   // sortable float
        v = ((unsigned long long)u << 32) | (unsigned)k;
      }
      {
        const unsigned long long o1 = __shfl_xor(v, 16);
        v = v < o1 ? v : o1;
        const unsigned long long o2 = __shfl_xor(v, 32);
        v = v < o2 ? v : o2;
      }
      if (lane == 0) wred[rr][wv] = v;
    }
    __syncthreads();
    if (tid < 16 && c0 + tid < nf) {
      unsigned long long b = wred[tid][0];
#pragma unroll
      for (int i = 1; i < 4; ++i) b = b < wred[tid][i] ? b : wred[tid][i];
      atomicMin(packed + lidx[tid], b);
    }
    __syncthreads();
  }
  // last-block fixup of indices / hist
  __threadfence();
  if (tid == 0) isLast = (atomicAdd(&misc[2], 1) == 511) ? 1 : 0;
  __syncthreads();
  if (isLast) {
    for (int f = tid; f < nf; f += 256) {
      const int r = list[f];
      const int fin = (int)(packed[r] & 0xFFFFFFFFull);
      const int old = fidx[r];
      if (fin != old) {
        fidx[r] = fin;
        outidxf[r] = (float)fin;
        atomicSub(&hist[old], 1);
        atomicAdd(&hist[fin], 1);
      }
    }
  }
}

// ================= gather + loss; last block: perplexity + scalars ==========
__global__ __launch_bounds__(256) void gather_k(
    const float* __restrict__ z, const float* __restrict__ cb,
    const int* __restrict__ idx, float* __restrict__ out,
    int* __restrict__ misc, const int* __restrict__ hist,
    float* __restrict__ out_tail) {
  float* lossp = (float*)&misc[0];
  const int e = (blockIdx.x * 256 + threadIdx.x) * 4;  // [b][c][hw], hw%4==0
  const int hw = e & 1023;
  const int bc = e >> 10;
  const int c = bc & 255;
  const int bimg = bc >> 8;
  const int n = (bimg << 10) + hw;
  const int4 k4 = *(const int4*)(idx + n);
  const float4 zv = *(const float4*)(z + e);
  const float q0 = cb[(size_t)k4.x * 256 + c];
  const float q1 = cb[(size_t)k4.y * 256 + c];
  const float q2 = cb[(size_t)k4.z * 256 + c];
  const float q3 = cb[(size_t)k4.w * 256 + c];
  const float d0 = q0 - zv.x, d1 = q1 - zv.y, d2 = q2 - zv.z, d3 = q3 - zv.w;
  float4 ov = {zv.x + d0, zv.y + d1, zv.z + d2, zv.w + d3};  // mirrors z+(q-z)
  *(float4*)(out + e) = ov;
  float t = d0 * d0 + d1 * d1 + d2 * d2 + d3 * d3;
  const int lane = threadIdx.x & 63, wid = threadIdx.x >> 6;
  for (int off = 32; off; off >>= 1) t += __shfl_down(t, off);
  __shared__ float ls[4];
  __shared__ int isLast;
  if (lane == 0) ls[wid] = t;
  __syncthreads();
  if (threadIdx.x == 0) {
    atomicAdd(lossp, ls[0] + ls[1] + ls[2] + ls[3]);
    __threadfence();
    isLast = (atomicAdd(&misc[3], 1) == 4095) ? 1 : 0;
  }
  __syncthreads();
  if (isLast) {
    float part = 0.f;
    for (int k = threadIdx.x; k < KCB; k += 256) {
      const float p = (float)hist[k] * (1.0f / 16384.0f);
      part += p * logf(fmaxf(p, 1e-10f));
    }
    for (int off = 32; off; off >>= 1) part += __shfl_down(part, off);
    __shared__ float ps[4];
    if (lane == 0) ps[wid] = part;
    __syncthreads();
    if (threadIdx.x == 0) {
      out_tail[0] = expf(-(ps[0] + ps[1] + ps[2] + ps[3]));  // perplexity
      const float lsum = atomicAdd(lossp, 0.0f);             // coherent read
      const float mean = lsum * (1.0f / 4194304.0f);
      out_tail[1] = mean;                                    // loss_vq
      out_tail[2] = mean;                                    // loss_commit
    }
  }
}

extern "C" void kernel_launch(void* const* d_in, const int* in_sizes, int n_in,
                              void* d_out, int out_size, void* d_ws,
                              size_t ws_size, hipStream_t stream) {
  const float* z = (const float*)d_in[0];
  const float* cb = (const float*)d_in[1];
  float* out = (float*)d_out;
  char* ws = (char*)d_ws;

  unsigned long long* packed = (unsigned long long*)(ws + OFF_PACKED);
  unsigned short* A = (unsigned short*)(ws + OFF_A);
  unsigned short* B = (unsigned short*)(ws + OFF_B);
  float* zt = (float*)(ws + OFF_ZT);
  float* nrm = (float*)(ws + OFF_NRM);
  float* pm1 = (float*)(ws + OFF_PM1);
  float* pm2 = (float*)(ws + OFF_PM2);
  int* pidx = (int*)(ws + OFF_PIDX);
  int* fidx = (int*)(ws + OFF_FIDX);
  int* list = (int*)(ws + OFF_LIST);
  int* hist = (int*)(ws + OFF_HIST);
  int* misc = (int*)(ws + OFF_MISC);
  float* outidxf = out + 4194304;
  float* out_tail = out + 4210688;

  prep_k<<<3104, 256, 0, stream>>>(z, cb, A, B, zt, nrm, hist, misc);
  vq_mfma_k<<<dim3(NNB, 128), 256, 0, stream>>>(A, B, nrm, pm1, pm2, pidx);
  reduce_k<<<64, 256, 0, stream>>>(pm1, pm2, pidx, fidx, outidxf, hist, packed,
                                   list, misc);
  cleanup_k<<<512, 256, 0, stream>>>(zt, cb, nrm, list, misc, packed, fidx,
                                     outidxf, hist);
  gather_k<<<4096, 256, 0, stream>>>(z, cb, fidx, out, misc, hist, out_tail);
}

// Round 7
// 469.371 us; speedup vs baseline: 1.5051x; 1.2551x over previous
//
#include <hip/hip_runtime.h>
#include <math.h>

typedef __attribute__((ext_vector_type(8))) __bf16 bf16x8;
typedef __attribute__((ext_vector_type(4))) float floatx4;

#define NROW 16384
#define KCB  8192
#define TAU  0.05f          // gap threshold for exact-recompute guard
#define NNB  32             // KCB / 256 n-blocks

// workspace byte offsets
#define OFF_PACKED 0u                    // 16384*8
#define OFF_A      131072u               // 16384*512*2 (zh|zl dedup)
#define OFF_B      16908288u             // 8192*512*2 (eh|el dedup)
#define OFF_ZT     25296896u             // 16384*256*4 fp32 z transposed
#define OFF_NRM    42074112u             // 8192*4
#define OFF_PM1    42106880u             // 32*16384*4
#define OFF_PM2    44204032u
#define OFF_PIDX   46301184u
#define OFF_FIDX   48398336u             // 16384*4
#define OFF_LIST   48463872u             // 16384*4
#define OFF_FLAG   48529408u             // 16384*4
#define OFF_HIST   48594944u             // 8192*4
#define OFF_MISC   48627712u             // [0] loss f32, [1] cnt

__device__ __forceinline__ unsigned short f2bf(float f) {  // RNE fp32->bf16
  unsigned u = __float_as_uint(f);
  return (unsigned short)((u + 0x7FFFu + ((u >> 16) & 1u)) >> 16);
}
__device__ __forceinline__ float bf2f(unsigned short b) {
  return __uint_as_float(((unsigned)b) << 16);
}
__device__ __forceinline__ unsigned pack2(unsigned short a, unsigned short b) {
  return (unsigned)a | ((unsigned)b << 16);
}
__device__ __forceinline__ void gld16(const void* g, void* l) {
  __builtin_amdgcn_global_load_lds(
      (const __attribute__((address_space(1))) unsigned int*)g,
      (__attribute__((address_space(3))) unsigned int*)l, 16, 0, 0);
}

// ================= fused prep =================
// bid <1024: A-prep (z transpose -> A'[n][512]=[zh|zl] bf16 + zt[n][256] fp32)
// 1024..3071: B-prep (B'[e][512]=[eh|el] bf16 + norms)
// 3072..3103: zero hist (+ misc on first)
__global__ __launch_bounds__(256) void prep_k(
    const float* __restrict__ z, const float* __restrict__ cb,
    unsigned short* __restrict__ A, unsigned short* __restrict__ B,
    float* __restrict__ zt, float* __restrict__ nrm, int* __restrict__ hist,
    int* __restrict__ misc) {
  const int tid = threadIdx.x;
  if (blockIdx.x < 1024) {
    __shared__ float t[64][65];
    const int bb = blockIdx.x >> 6;
    const int hw0 = ((blockIdx.x >> 2) & 15) * 64;
    const int c0 = (blockIdx.x & 3) * 64;
    const int cl = tid >> 2, h4 = (tid & 3) * 16;
    const float* src = z + ((size_t)(bb * 256 + c0 + cl)) * 1024 + hw0 + h4;
#pragma unroll
    for (int j = 0; j < 4; ++j) {
      const float4 v = *(const float4*)(src + 4 * j);
      t[cl][h4 + 4 * j + 0] = v.x; t[cl][h4 + 4 * j + 1] = v.y;
      t[cl][h4 + 4 * j + 2] = v.z; t[cl][h4 + 4 * j + 3] = v.w;
    }
    __syncthreads();
    const int hl = tid >> 2, cq = (tid & 3) * 16;
    const size_t n = (size_t)bb * 1024 + hw0 + hl;
    float fv[16];
    unsigned short hi[16], lo[16];
#pragma unroll
    for (int j = 0; j < 16; ++j) {
      const float f = t[cq + j][hl];
      fv[j] = f;
      const unsigned short h = f2bf(f);
      hi[j] = h;
      lo[j] = f2bf(f - bf2f(h));
    }
    unsigned short* dst = A + n * 512 + c0 + cq;
    uint4 h0 = {pack2(hi[0], hi[1]), pack2(hi[2], hi[3]), pack2(hi[4], hi[5]), pack2(hi[6], hi[7])};
    uint4 h1 = {pack2(hi[8], hi[9]), pack2(hi[10], hi[11]), pack2(hi[12], hi[13]), pack2(hi[14], hi[15])};
    uint4 l0 = {pack2(lo[0], lo[1]), pack2(lo[2], lo[3]), pack2(lo[4], lo[5]), pack2(lo[6], lo[7])};
    uint4 l1 = {pack2(lo[8], lo[9]), pack2(lo[10], lo[11]), pack2(lo[12], lo[13]), pack2(lo[14], lo[15])};
    *(uint4*)(dst) = h0;        *(uint4*)(dst + 8) = h1;       // zh at [c]
    *(uint4*)(dst + 256) = l0;  *(uint4*)(dst + 264) = l1;     // zl at [256+c]
    float* zp = zt + n * 256 + c0 + cq;
#pragma unroll
    for (int j = 0; j < 4; ++j) {
      float4 v = {fv[4 * j], fv[4 * j + 1], fv[4 * j + 2], fv[4 * j + 3]};
      *(float4*)(zp + 4 * j) = v;
    }
  } else if (blockIdx.x < 3072) {
    const int w = tid >> 6, lane = tid & 63;
    const int row = (blockIdx.x - 1024) * 4 + w;
    const float4 v = *(const float4*)(cb + (size_t)row * 256 + lane * 4);
    float s = v.x * v.x + v.y * v.y + v.z * v.z + v.w * v.w;
    float f[4] = {v.x, v.y, v.z, v.w};
    ushort4 hv, lv;
    unsigned short* hp = (unsigned short*)&hv;
    unsigned short* lp = (unsigned short*)&lv;
#pragma unroll
    for (int j = 0; j < 4; ++j) {
      const unsigned short h = f2bf(f[j]);
      hp[j] = h;
      lp[j] = f2bf(f[j] - bf2f(h));
    }
    unsigned short* dst = B + (size_t)row * 512 + lane * 4;
    *(ushort4*)(dst) = hv;          // eh
    *(ushort4*)(dst + 256) = lv;    // el
    for (int off = 32; off; off >>= 1) s += __shfl_down(s, off);
    if (lane == 0) nrm[row] = s;
  } else {
    const int i = blockIdx.x - 3072;   // 0..31
    hist[i * 256 + tid] = 0;
    if (i == 0 && tid < 2) misc[tid] = 0;
  }
}

// ================= main: bf16 MFMA distance GEMM + fused top-2 argmin ========
// R4-proven structure (272 us, MfmaUtil 33%, conflicts ~0), dedup'd A'/B'
// with per-kc offset remap. terms: kc 0-3 zh.eh | 4-7 zh.el | 8-11 zl.eh
__global__ __launch_bounds__(256, 2) void vq_mfma_k(
    const unsigned short* __restrict__ A, const unsigned short* __restrict__ Bm,
    const float* __restrict__ nrm, float* __restrict__ pm1,
    float* __restrict__ pm2, int* __restrict__ pidx) {
  __shared__ unsigned short As[128 * 64];  // 16 KB
  __shared__ unsigned short Bs[256 * 64];  // 32 KB

  const int tid = threadIdx.x;
  const int mb = blockIdx.y, nb = blockIdx.x;
  const int w = tid >> 6, lane = tid & 63;
  const int quad = lane >> 4, lrow = lane & 15;

  const int sr = tid >> 3, ss = tid & 7;
  const int sq = ss ^ (sr & 7);
  const unsigned short* gA = A + (size_t)(mb * 128 + sr) * 512 + sq * 8;
  const unsigned short* gB = Bm + (size_t)(nb * 256 + sr) * 512 + sq * 8;
  unsigned short* lA = As + sr * 64 + ss * 8;
  unsigned short* lB = Bs + sr * 64 + ss * 8;

  floatx4 acc[8][4];
#pragma unroll
  for (int i = 0; i < 8; ++i)
#pragma unroll
    for (int j = 0; j < 4; ++j) acc[i][j] = (floatx4){0.f, 0.f, 0.f, 0.f};

  for (int kc = 0; kc < 12; ++kc) {
    const int koA = ((kc & 3) << 6) + (kc >= 8 ? 256 : 0);
    const int koB = ((kc & 3) << 6) + ((kc >= 4 && kc < 8) ? 256 : 0);
#pragma unroll
    for (int i = 0; i < 4; ++i)
      gld16(gA + (size_t)(i * 32) * 512 + koA, lA + i * 32 * 64);
#pragma unroll
    for (int i = 0; i < 8; ++i)
      gld16(gB + (size_t)(i * 32) * 512 + koB, lB + i * 32 * 64);
    __syncthreads();
#pragma unroll
    for (int ks = 0; ks < 2; ++ks) {
      bf16x8 af[8], bf[4];
#pragma unroll
      for (int mt = 0; mt < 8; ++mt) {
        const int row = mt * 16 + lrow;
        const int slot = (ks * 4 + quad) ^ (row & 7);
        af[mt] = *(const bf16x8*)(As + row * 64 + slot * 8);
      }
#pragma unroll
      for (int nt = 0; nt < 4; ++nt) {
        const int row = w * 64 + nt * 16 + lrow;
        const int slot = (ks * 4 + quad) ^ (row & 7);
        bf[nt] = *(const bf16x8*)(Bs + row * 64 + slot * 8);
      }
#pragma unroll
      for (int mt = 0; mt < 8; ++mt)
#pragma unroll
        for (int nt = 0; nt < 4; ++nt)
          acc[mt][nt] = __builtin_amdgcn_mfma_f32_16x16x32_bf16(
              af[mt], bf[nt], acc[mt][nt], 0, 0, 0);
    }
    __syncthreads();
  }

  // ---- epilogue: score = nrm[k] - 2*dot; top-2 per row over 256 cols ----
  float nr[4];
#pragma unroll
  for (int nt = 0; nt < 4; ++nt) nr[nt] = nrm[nb * 256 + w * 64 + nt * 16 + lrow];

  float* Lm1 = (float*)As;             // overlay (As dead after loop)
  int* Li1 = (int*)(As + 2048);
  float* Lm2 = (float*)(As + 4096);
#pragma unroll
  for (int mt = 0; mt < 8; ++mt) {
#pragma unroll
    for (int p = 0; p < 4; ++p) {
      float m1 = 3e38f, m2 = 3e38f;
      int i1 = 0;
#pragma unroll
      for (int nt = 0; nt < 4; ++nt) {
        const float s = nr[nt] - 2.0f * acc[mt][nt][p];
        const int kg = nb * 256 + w * 64 + nt * 16 + lrow;
        if (s < m1) { m2 = m1; m1 = s; i1 = kg; }
        else m2 = fminf(m2, s);
      }
      for (int d = 1; d < 16; d <<= 1) {   // merge across 16 lrow lanes
        const float om1 = __shfl_xor(m1, d);
        const int oi1 = __shfl_xor(i1, d);
        const float om2 = __shfl_xor(m2, d);
        if (om1 < m1) { m2 = fminf(m1, om2); m1 = om1; i1 = oi1; }
        else          { m2 = fminf(m2, om1); }
      }
      if (lrow == 0) {
        const int rl = mt * 16 + quad * 4 + p;
        Lm1[rl * 4 + w] = m1; Li1[rl * 4 + w] = i1; Lm2[rl * 4 + w] = m2;
      }
    }
  }
  __syncthreads();
  if (tid < 128) {
    float m1 = Lm1[tid * 4], m2 = Lm2[tid * 4];
    int i1 = Li1[tid * 4];
#pragma unroll
    for (int v = 1; v < 4; ++v) {
      const float om1 = Lm1[tid * 4 + v], om2 = Lm2[tid * 4 + v];
      const int oi1 = Li1[tid * 4 + v];
      if (om1 < m1) { m2 = fminf(m1, om2); m1 = om1; i1 = oi1; }
      else          { m2 = fminf(m2, om1); }
    }
    const int r = mb * 128 + tid;
    pm1[(size_t)nb * NROW + r] = m1;
    pm2[(size_t)nb * NROW + r] = m2;
    pidx[(size_t)nb * NROW + r] = i1;
  }
}

// ================= reduce partials + provisional finalize =================
__global__ __launch_bounds__(256) void reduce_k(
    const float* __restrict__ pm1, const float* __restrict__ pm2,
    const int* __restrict__ pidx, int* __restrict__ fidx,
    float* __restrict__ outidxf, int* __restrict__ hist,
    unsigned long long* __restrict__ packed, int* __restrict__ list,
    int* __restrict__ flag, int* __restrict__ misc) {
  const int r = blockIdx.x * 256 + threadIdx.x;
  float m1 = 3e38f, m2 = 3e38f;
  int i1 = 0;
  for (int nb = 0; nb < NNB; ++nb) {   // ascending k: strict < keeps first
    const float om1 = pm1[(size_t)nb * NROW + r];
    const float om2 = pm2[(size_t)nb * NROW + r];
    const int oi1 = pidx[(size_t)nb * NROW + r];
    if (om1 < m1) { m2 = fminf(m1, om2); m1 = om1; i1 = oi1; }
    else          { m2 = fminf(m2, om1); }
  }
  fidx[r] = i1;
  outidxf[r] = (float)i1;
  atomicAdd(&hist[i1], 1);
  const int fl = (m2 - m1 < TAU) ? 1 : 0;
  flag[r] = fl;
  if (fl) {
    packed[r] = 0xFFFFFFFFFFFFFFFFull;
    const int p = atomicAdd(&misc[1], 1);
    list[p] = r;
  }
}

// ================= exact fp32 recompute (batched over flagged rows) =========
// 512 blocks x 16 k each: cb rows cached in registers ONCE, flagged rows
// streamed through LDS. No fences — consumers are later kernels.
__global__ __launch_bounds__(256) void cleanup_k(
    const float* __restrict__ zt, const float* __restrict__ cb,
    const float* __restrict__ nrm, const int* __restrict__ list,
    const int* __restrict__ misc, unsigned long long* __restrict__ packed) {
  __shared__ float zr[16][256];
  __shared__ int lidx[16];
  __shared__ unsigned long long wred[16][4];
  const int tid = threadIdx.x;
  const int lane = tid & 63, wv = tid >> 6;
  const int nf = misc[1];
  const int k = blockIdx.x * 16 + (tid >> 4);
  const int cs1 = tid & 15;
  float creg[16];
#pragma unroll
  for (int j = 0; j < 16; ++j) creg[j] = cb[(size_t)k * 256 + cs1 + 16 * j];
  const float nk = nrm[k];

  for (int c0 = 0; c0 < nf; c0 += 16) {
    if (tid < 16) lidx[tid] = list[(c0 + tid < nf) ? (c0 + tid) : c0];
    __syncthreads();
#pragma unroll
    for (int j = 0; j < 16; ++j)
      zr[j][tid] = zt[(size_t)lidx[j] * 256 + tid];
    __syncthreads();
    const int rmax = (nf - c0 < 16) ? (nf - c0) : 16;
    for (int rr = 0; rr < rmax; ++rr) {
      float p = 0.f;
#pragma unroll
      for (int j = 0; j < 16; ++j) p += creg[j] * zr[rr][cs1 + 16 * j];
      p += __shfl_xor(p, 1); p += __shfl_xor(p, 2);
      p += __shfl_xor(p, 4); p += __shfl_xor(p, 8);
      unsigned long long v = 0xFFFFFFFFFFFFFFFFull;
      if (cs1 == 0) {
        const float s = nk - 2.f * p;
        unsigned u = __float_as_uint(s);
        u ^= (unsigned)((int)u >> 31) | 0x80000000u;   // sortable float
        v = ((unsigned long long)u << 32) | (unsigned)k;
      }
      {
        const unsigned long long o1 = __shfl_xor(v, 16);
        v = v < o1 ? v : o1;
        const unsigned long long o2 = __shfl_xor(v, 32);
        v = v < o2 ? v : o2;
      }
      if (lane == 0) wred[rr][wv] = v;
    }
    __syncthreads();
    if (tid < 16 && c0 + tid < nf) {
      unsigned long long b = wred[tid][0];
#pragma unroll
      for (int i = 1; i < 4; ++i) b = b < wred[tid][i] ? b : wred[tid][i];
      atomicMin(packed + lidx[tid], b);
    }
    __syncthreads();
  }
}

// ================= gather + loss (final index resolved inline) ==============
__global__ __launch_bounds__(256) void gather_k(
    const float* __restrict__ z, const float* __restrict__ cb,
    const int* __restrict__ idx, const int* __restrict__ flag,
    const unsigned long long* __restrict__ packed, float* __restrict__ out,
    float* __restrict__ lossp) {
  const int e = (blockIdx.x * 256 + threadIdx.x) * 4;  // [b][c][hw], hw%4==0
  const int hw = e & 1023;
  const int bc = e >> 10;
  const int c = bc & 255;
  const int bimg = bc >> 8;
  const int n = (bimg << 10) + hw;
  int4 k4 = *(const int4*)(idx + n);
  const int4 f4 = *(const int4*)(flag + n);
  if (f4.x) k4.x = (int)(packed[n + 0] & 0xFFFFFFFFull);
  if (f4.y) k4.y = (int)(packed[n + 1] & 0xFFFFFFFFull);
  if (f4.z) k4.z = (int)(packed[n + 2] & 0xFFFFFFFFull);
  if (f4.w) k4.w = (int)(packed[n + 3] & 0xFFFFFFFFull);
  const float4 zv = *(const float4*)(z + e);
  const float q0 = cb[(size_t)k4.x * 256 + c];
  const float q1 = cb[(size_t)k4.y * 256 + c];
  const float q2 = cb[(size_t)k4.z * 256 + c];
  const float q3 = cb[(size_t)k4.w * 256 + c];
  const float d0 = q0 - zv.x, d1 = q1 - zv.y, d2 = q2 - zv.z, d3 = q3 - zv.w;
  float4 ov = {zv.x + d0, zv.y + d1, zv.z + d2, zv.w + d3};  // mirrors z+(q-z)
  *(float4*)(out + e) = ov;
  float t = d0 * d0 + d1 * d1 + d2 * d2 + d3 * d3;
  const int lane = threadIdx.x & 63, wid = threadIdx.x >> 6;
  for (int off = 32; off; off >>= 1) t += __shfl_down(t, off);
  __shared__ float ls[4];
  if (lane == 0) ls[wid] = t;
  __syncthreads();
  if (threadIdx.x == 0) atomicAdd(lossp, ls[0] + ls[1] + ls[2] + ls[3]);
}

// ================= final: hist deltas, outidxf fixups, perplexity, losses ===
__global__ __launch_bounds__(256) void final_k(
    const int* __restrict__ misc, const int* __restrict__ list,
    const unsigned long long* __restrict__ packed, const int* __restrict__ fidx,
    const int* __restrict__ hist, float* __restrict__ outidxf,
    float* __restrict__ out_tail) {
  __shared__ int dh[KCB];             // 32 KB delta-hist
  const int tid = threadIdx.x;
  const float* lossp = (const float*)&misc[0];
  const int nf = misc[1];
  for (int k = tid; k < KCB; k += 256) dh[k] = 0;
  __syncthreads();
  for (int f = tid; f < nf; f += 256) {
    const int r = list[f];
    const int fin = (int)(packed[r] & 0xFFFFFFFFull);
    const int old = fidx[r];
    if (fin != old) {
      atomicAdd(&dh[fin], 1);
      atomicSub(&dh[old], 1);
      outidxf[r] = (float)fin;
    }
  }
  __syncthreads();
  float part = 0.f;
  for (int k = tid; k < KCB; k += 256) {
    const float p = (float)(hist[k] + dh[k]) * (1.0f / 16384.0f);
    part += p * logf(fmaxf(p, 1e-10f));
  }
  const int lane = tid & 63, wid = tid >> 6;
  for (int off = 32; off; off >>= 1) part += __shfl_down(part, off);
  __shared__ float ps[4];
  if (lane == 0) ps[wid] = part;
  __syncthreads();
  if (tid == 0) {
    out_tail[0] = expf(-(ps[0] + ps[1] + ps[2] + ps[3]));  // perplexity
    const float mean = *lossp * (1.0f / 4194304.0f);
    out_tail[1] = mean;                                    // loss_vq
    out_tail[2] = mean;                                    // loss_commit
  }
}

extern "C" void kernel_launch(void* const* d_in, const int* in_sizes, int n_in,
                              void* d_out, int out_size, void* d_ws,
                              size_t ws_size, hipStream_t stream) {
  const float* z = (const float*)d_in[0];
  const float* cb = (const float*)d_in[1];
  float* out = (float*)d_out;
  char* ws = (char*)d_ws;

  unsigned long long* packed = (unsigned long long*)(ws + OFF_PACKED);
  unsigned short* A = (unsigned short*)(ws + OFF_A);
  unsigned short* B = (unsigned short*)(ws + OFF_B);
  float* zt = (float*)(ws + OFF_ZT);
  float* nrm = (float*)(ws + OFF_NRM);
  float* pm1 = (float*)(ws + OFF_PM1);
  float* pm2 = (float*)(ws + OFF_PM2);
  int* pidx = (int*)(ws + OFF_PIDX);
  int* fidx = (int*)(ws + OFF_FIDX);
  int* list = (int*)(ws + OFF_LIST);
  int* flag = (int*)(ws + OFF_FLAG);
  int* hist = (int*)(ws + OFF_HIST);
  int* misc = (int*)(ws + OFF_MISC);
  float* outidxf = out + 4194304;
  float* out_tail = out + 4210688;

  prep_k<<<3104, 256, 0, stream>>>(z, cb, A, B, zt, nrm, hist, misc);
  vq_mfma_k<<<dim3(NNB, 128), 256, 0, stream>>>(A, B, nrm, pm1, pm2, pidx);
  reduce_k<<<64, 256, 0, stream>>>(pm1, pm2, pidx, fidx, outidxf, hist, packed,
                                   list, flag, misc);
  cleanup_k<<<512, 256, 0, stream>>>(zt, cb, nrm, list, misc, packed);
  gather_k<<<4096, 256, 0, stream>>>(z, cb, fidx, flag, packed, out,
                                     (float*)&misc[0]);
  final_k<<<1, 256, 0, stream>>>(misc, list, packed, fidx, hist, outidxf,
                                 out_tail);
}